// Round 9
// baseline (153.184 us; speedup 1.0000x reference)
//
#include <hip/hip_runtime.h>

// MHA: B=4, S=2048, D_MODEL=512, H=8, D_HEAD=64
// Wt transpose -> QKV proj GEMMs (one launch) -> flash attn -> out proj GEMM
// attn r9: K AND V double-buffered via global_load_lds, both prefetched one
// full tile ahead; ONE barrier per tile (end: vmcnt(0) drain + syncthreads).
// Ps: stride-64 + XOR swizzle (fits 40KB LDS = 4 blocks/CU); write->read
// ordered by lgkmcnt(0) fence + sched_barrier(0) (r7-proven pair).
// Softmax: max3 triples, cross-lane max shuffles only in rare rescale branch.
// gemm_out: 128x64 tiles -> 512 blocks (2/CU).

typedef unsigned short u16;
typedef __bf16 bf16x8 __attribute__((ext_vector_type(8)));
typedef float  f32x4  __attribute__((ext_vector_type(4)));

__device__ __forceinline__ u16 f2bf(float x) {
  unsigned u = __float_as_uint(x);
  u += 0x7fffu + ((u >> 16) & 1u);   // RNE
  return (u16)(u >> 16);
}

__device__ __forceinline__ unsigned cvtpk(float lo, float hi) {
  unsigned r;
  asm("v_cvt_pk_bf16_f32 %0, %1, %2" : "=v"(r) : "v"(lo), "v"(hi));
  return r;
}

__device__ __forceinline__ f32x4 mfma16(bf16x8 a, bf16x8 b, f32x4 c) {
  return __builtin_amdgcn_mfma_f32_16x16x32_bf16(a, b, c, 0, 0, 0);
}

// async 16B/lane global->LDS; lds dest is wave-uniform base (HW adds lane*16)
__device__ __forceinline__ void gl16(const u16* g, u16* l) {
  __builtin_amdgcn_global_load_lds(
      (const __attribute__((address_space(1))) void*)g,
      (__attribute__((address_space(3))) void*)l, 16, 0, 0);
}

#define MX3(a, b, c) fmaxf(fmaxf((a), (b)), (c))

// ---- W[k][n] fp32 -> Wt[n][k] bf16, all 4 weights in one launch ----
__global__ __launch_bounds__(256) void wtrans_k(const float* __restrict__ W0,
                                                const float* __restrict__ W1,
                                                const float* __restrict__ W2,
                                                const float* __restrict__ W3,
                                                u16* __restrict__ Wt) {
  int sel = blockIdx.y;
  const float* W = sel == 0 ? W0 : sel == 1 ? W1 : sel == 2 ? W2 : W3;
  int idx = blockIdx.x * 256 + threadIdx.x;
  int k = idx >> 9, n = idx & 511;
  Wt[sel * 262144 + n * 512 + k] = f2bf(W[idx]);
}

// ---- GEMM body: A[8192x512] @ Bt^T + bias (Bt is [n][k] bf16) ----
// OUT_MODE: 0 bf16 [m][n], 1 bf16 vT[(b*8+h)*64+d][s], 2 fp32 [m][n]
// BN: block tile N (128 or 64); block tile M fixed at 128.
template <bool A_BF16, int OUT_MODE, int BN>
__device__ __forceinline__ void gemm_body(const void* __restrict__ Ap,
                                          const u16* __restrict__ Bt,
                                          const float* __restrict__ bias,
                                          void* __restrict__ outp, int bidx) {
  constexpr int NF = BN / 32;        // B n-frags per wave (4 or 2)
  constexpr int NBN = 512 / BN;      // n-tiles
  __shared__ __align__(16) u16 As[128][72];
  __shared__ __align__(16) u16 Bs[BN][72];
  int tid = threadIdx.x;
  int lane = tid & 63, wid = tid >> 6;
  int wm = wid >> 1, wn = wid & 1;
  int lr = lane & 15, lg = lane >> 4;
  int bm = bidx / NBN, bn = bidx % NBN;

  f32x4 acc[4][NF];
#pragma unroll
  for (int i = 0; i < 4; ++i)
#pragma unroll
    for (int j = 0; j < NF; ++j) {
      f32x4 z = {0.f, 0.f, 0.f, 0.f};
      acc[i][j] = z;
    }

  for (int kt = 0; kt < 8; ++kt) {
    int k0 = kt * 64;
    if (!A_BF16) {
      const float* A = (const float*)Ap;
#pragma unroll
      for (int i = 0; i < 8; ++i) {
        int idx = i * 256 + tid;
        int row = idx >> 4, c4 = idx & 15;
        float4 v = *(const float4*)(A + (size_t)(bm * 128 + row) * 512 + k0 + c4 * 4);
        ushort4 pk = make_ushort4(f2bf(v.x), f2bf(v.y), f2bf(v.z), f2bf(v.w));
        *(ushort4*)&As[row][c4 * 4] = pk;
      }
    } else {
      const u16* A = (const u16*)Ap;
#pragma unroll
      for (int i = 0; i < 4; ++i) {
        int idx = i * 256 + tid;
        int row = idx >> 3, c8 = idx & 7;
        uint4 v = *(const uint4*)(A + (size_t)(bm * 128 + row) * 512 + k0 + c8 * 8);
        *(uint4*)&As[row][c8 * 8] = v;
      }
    }
#pragma unroll
    for (int i = 0; i < BN / 32; ++i) {
      int idx = i * 256 + tid;
      int row = idx >> 3, c8 = idx & 7;
      uint4 v = *(const uint4*)(Bt + (size_t)(bn * BN + row) * 512 + k0 + c8 * 8);
      *(uint4*)&Bs[row][c8 * 8] = v;
    }
    __syncthreads();
#pragma unroll
    for (int kk = 0; kk < 2; ++kk) {
      bf16x8 af[4], bfr[NF];
#pragma unroll
      for (int mf = 0; mf < 4; ++mf)
        af[mf] = *(const bf16x8*)&As[wm * 64 + mf * 16 + lr][kk * 32 + lg * 8];
#pragma unroll
      for (int nf = 0; nf < NF; ++nf)
        bfr[nf] = *(const bf16x8*)&Bs[wn * (BN / 2) + nf * 16 + lr][kk * 32 + lg * 8];
#pragma unroll
      for (int mf = 0; mf < 4; ++mf)
#pragma unroll
        for (int nf = 0; nf < NF; ++nf)
          acc[mf][nf] = mfma16(af[mf], bfr[nf], acc[mf][nf]);
    }
    __syncthreads();
  }

#pragma unroll
  for (int mf = 0; mf < 4; ++mf) {
#pragma unroll
    for (int nf = 0; nf < NF; ++nf) {
      int m = bm * 128 + wm * 64 + mf * 16 + lg * 4;
      int n = bn * BN + wn * (BN / 2) + nf * 16 + lr;
      float bia = bias[n];
      if (OUT_MODE == 0) {
        u16* o = (u16*)outp;
#pragma unroll
        for (int r = 0; r < 4; ++r)
          o[(size_t)(m + r) * 512 + n] = f2bf(acc[mf][nf][r] + bia);
      } else if (OUT_MODE == 2) {
        float* o = (float*)outp;
#pragma unroll
        for (int r = 0; r < 4; ++r)
          o[(size_t)(m + r) * 512 + n] = acc[mf][nf][r] + bia;
      } else {
        u16* o = (u16*)outp;
        int b = m >> 11, s = m & 2047;
        int h = n >> 6, d = n & 63;
        ushort4 pk = make_ushort4(f2bf(acc[mf][nf][0] + bia), f2bf(acc[mf][nf][1] + bia),
                                  f2bf(acc[mf][nf][2] + bia), f2bf(acc[mf][nf][3] + bia));
        *(ushort4*)&o[(size_t)((b * 8 + h) * 64 + d) * 2048 + s] = pk;
      }
    }
  }
}

// QKV projections in one launch: blockIdx.y selects Q/K/V
__global__ __launch_bounds__(256) void qkv_k(const float* __restrict__ Q,
                                             const float* __restrict__ K,
                                             const float* __restrict__ V,
                                             const u16* __restrict__ Wt,
                                             const float* __restrict__ bq,
                                             const float* __restrict__ bk,
                                             const float* __restrict__ bv,
                                             u16* __restrict__ outbase) {
  int sel = blockIdx.y;
  const float* A = sel == 0 ? Q : sel == 1 ? K : V;
  const float* bia = sel == 0 ? bq : sel == 1 ? bk : bv;
  const u16* Bt = Wt + (size_t)sel * 262144;
  u16* out = outbase + (size_t)sel * 8192 * 512;
  if (sel == 2)
    gemm_body<false, 1, 128>(A, Bt, bia, out, blockIdx.x);
  else
    gemm_body<false, 0, 128>(A, Bt, bia, out, blockIdx.x);
}

__global__ __launch_bounds__(256) void gemm_out_k(const void* __restrict__ Ap,
                                                  const u16* __restrict__ Bt,
                                                  const float* __restrict__ bias,
                                                  void* __restrict__ outp) {
  gemm_body<true, 2, 64>(Ap, Bt, bias, outp, blockIdx.x);
}

// ---- flash attention ----
// S^T = mfma(K,Q): lane owns q = lane&15, keys nf*16+lg*4+r -> in-register softmax.
// O^T = mfma(V,P): oacc q-index = lane&15 too -> per-lane m/l, no shuffles.
// K/V both dbuf via global_load_lds; one barrier per tile.
__global__ __launch_bounds__(256) void attn_k(const u16* __restrict__ q,
                                              const u16* __restrict__ kmat,
                                              const u16* __restrict__ vT,
                                              u16* __restrict__ z) {
  __shared__ __align__(16) u16 Ks[2][64][64];   // [buf][key][d], swizzled content
  __shared__ __align__(16) u16 Vs[2][64][64];   // [buf][d][key], swizzled content
  __shared__ __align__(16) u16 Ps[4][16][64];   // per-wave P[q][key], XOR swizzled
  const float C = 0.125f * 1.44269504f;         // 1/sqrt(64) * log2(e)
  int tid = threadIdx.x;
  int lane = tid & 63, w = tid >> 6;
  int lr = lane & 15, lg = lane >> 4;
  int bh = blockIdx.x >> 5, qt = blockIdx.x & 31;
  int b = bh >> 3, h = bh & 7;
  size_t qrow0 = (size_t)(b * 2048 + qt * 64 + w * 16);

  // Q as B-fragment: lane holds Q[q=lr][d = kf*32 + lg*8 + j]
  bf16x8 qf[2];
#pragma unroll
  for (int kf = 0; kf < 2; ++kf)
    qf[kf] = *(const bf16x8*)&q[(qrow0 + lr) * 512 + h * 64 + kf * 32 + lg * 8];

  f32x4 oacc[4];
#pragma unroll
  for (int j = 0; j < 4; ++j) {
    f32x4 zf = {0.f, 0.f, 0.f, 0.f};
    oacc[j] = zf;
  }
  float m = -1e30f, l = 0.f, negmC = 0.f;

  const u16* kbase = kmat + (size_t)(b * 2048) * 512 + h * 64;
  const u16* vbase = vT + (size_t)(bh * 64) * 2048;

  // staging coords: LDS idx = i*256 + tid; row = idx>>3, c8dst = idx&7.
  // Pre-swizzled SOURCE column: c8src = c8dst ^ (row&7); row&7 == (tid>>3)&7 for both i.
  int r0 = tid >> 3;                         // 0..31
  int c8s = (tid & 7) ^ (r0 & 7);
  // prologue: K(0),V(0) -> buf0
  gl16(&kbase[(size_t)r0 * 512 + c8s * 8],        &Ks[0][0][0] + w * 512);
  gl16(&kbase[(size_t)(r0 + 32) * 512 + c8s * 8], &Ks[0][0][0] + 2048 + w * 512);
  gl16(&vbase[(size_t)r0 * 2048 + c8s * 8],        &Vs[0][0][0] + w * 512);
  gl16(&vbase[(size_t)(r0 + 32) * 2048 + c8s * 8], &Vs[0][0][0] + 2048 + w * 512);
  asm volatile("s_waitcnt vmcnt(0)" ::: "memory");
  __syncthreads();

  for (int kt = 0; kt < 32; ++kt) {
    int cur = kt & 1;
    // issue K(kt+1), V(kt+1) -> buf^1 (drained at end-of-tile barrier)
    if (kt < 31) {
      u16* KL = &Ks[cur ^ 1][0][0];
      u16* VL = &Vs[cur ^ 1][0][0];
      gl16(&kbase[(size_t)((kt + 1) * 64 + r0) * 512 + c8s * 8],       KL + w * 512);
      gl16(&kbase[(size_t)((kt + 1) * 64 + r0 + 32) * 512 + c8s * 8],  KL + 2048 + w * 512);
      gl16(&vbase[(size_t)r0 * 2048 + (kt + 1) * 64 + c8s * 8],        VL + w * 512);
      gl16(&vbase[(size_t)(r0 + 32) * 2048 + (kt + 1) * 64 + c8s * 8], VL + 2048 + w * 512);
    }

    // S^T = K @ Q^T : sacc[nf][r] = S[q=lr][key = nf*16 + lg*4 + r]
    f32x4 sacc[4];
#pragma unroll
    for (int j = 0; j < 4; ++j) {
      f32x4 zf = {0.f, 0.f, 0.f, 0.f};
      sacc[j] = zf;
    }
#pragma unroll
    for (int kf = 0; kf < 2; ++kf) {
#pragma unroll
      for (int nf = 0; nf < 4; ++nf) {
        int row = nf * 16 + lr;
        bf16x8 kb = *(const bf16x8*)&Ks[cur][row][(kf * 32 + lg * 8) ^ ((row & 7) << 3)];
        sacc[nf] = mfma16(kb, qf[kf], sacc[nf]);
      }
    }

    // V B-fragment prefetch (V(kt) resident since last barrier; no waits)
    bf16x8 vb[2][4];
#pragma unroll
    for (int ks = 0; ks < 2; ++ks)
#pragma unroll
      for (int nfo = 0; nfo < 4; ++nfo) {
        int row = nfo * 16 + lr;
        vb[ks][nfo] = *(const bf16x8*)&Vs[cur][row][(ks * 32 + lg * 8) ^ ((row & 7) << 3)];
      }

    // per-lane 16-value max via max3 triples (8 ops)
    float t0 = MX3(sacc[0][0], sacc[0][1], sacc[0][2]);
    float t1 = MX3(sacc[0][3], sacc[1][0], sacc[1][1]);
    float t2 = MX3(sacc[1][2], sacc[1][3], sacc[2][0]);
    float t3 = MX3(sacc[2][1], sacc[2][2], sacc[2][3]);
    float t4 = MX3(sacc[3][0], sacc[3][1], sacc[3][2]);
    float mxl = fmaxf(MX3(t0, t1, t2), MX3(t3, t4, sacc[3][3]));

    // defer-max (T13): cross-lane max + rescale only in the rare branch.
    // Untriggered => m unchanged (consistent per q-row); triggered => uniform
    // (__all) so all lanes shuffle together.
    if (!__all(mxl - m <= 8.f)) {
      float mx = fmaxf(mxl, __shfl_xor(mxl, 16));
      mx = fmaxf(mx, __shfl_xor(mx, 32));
      float mnew = fmaxf(m, mx);
      float sc = __builtin_amdgcn_exp2f((m - mnew) * C);
      m = mnew;
      negmC = -m * C;
      l *= sc;
#pragma unroll
      for (int nfo = 0; nfo < 4; ++nfo)
#pragma unroll
        for (int r = 0; r < 4; ++r) oacc[nfo][r] *= sc;
    }

    // P = exp2(S*C - m*C), pack bf16 pairs, swizzled 8B stores
    float rsum = 0.f;
#pragma unroll
    for (int nf = 0; nf < 4; ++nf) {
      float p0 = __builtin_amdgcn_exp2f(fmaf(sacc[nf][0], C, negmC));
      float p1 = __builtin_amdgcn_exp2f(fmaf(sacc[nf][1], C, negmC));
      float p2 = __builtin_amdgcn_exp2f(fmaf(sacc[nf][2], C, negmC));
      float p3 = __builtin_amdgcn_exp2f(fmaf(sacc[nf][3], C, negmC));
      rsum += (p0 + p1) + (p2 + p3);
      uint2 pw = make_uint2(cvtpk(p0, p1), cvtpk(p2, p3));
      *(uint2*)&Ps[w][lr][(nf * 16 + lg * 4) ^ ((lr & 7) << 3)] = pw;
    }
    rsum += __shfl_xor(rsum, 16);
    rsum += __shfl_xor(rsum, 32);
    l += rsum;

    // Ps write->read ordering: fence + sched_barrier (r7-proven pair).
    // Pinned region = 2 Ps reads + 8 MFMAs only (V already in regs).
    asm volatile("s_waitcnt lgkmcnt(0)" ::: "memory");
    __builtin_amdgcn_sched_barrier(0);

    // O^T += V^T @ P^T : oacc[nfo][r] = O[q=lr][d = nfo*16 + lg*4 + r]
#pragma unroll
    for (int ks = 0; ks < 2; ++ks) {
      bf16x8 pa = *(const bf16x8*)&Ps[w][lr][(ks * 32 + lg * 8) ^ ((lr & 7) << 3)];
#pragma unroll
      for (int nfo = 0; nfo < 4; ++nfo)
        oacc[nfo] = mfma16(vb[ks][nfo], pa, oacc[nfo]);
    }

    // single end-of-tile barrier: K/V(kt+1) landed, all waves done with bufs
    asm volatile("s_waitcnt vmcnt(0)" ::: "memory");
    __syncthreads();
  }

  // normalize + vectorized store: lane owns q = lr, 4 consecutive d per nfo
  float rl = 1.f / l;
#pragma unroll
  for (int nfo = 0; nfo < 4; ++nfo) {
    uint2 pw = make_uint2(cvtpk(oacc[nfo][0] * rl, oacc[nfo][1] * rl),
                          cvtpk(oacc[nfo][2] * rl, oacc[nfo][3] * rl));
    *(uint2*)&z[(qrow0 + lr) * 512 + h * 64 + nfo * 16 + lg * 4] = pw;
  }
}

extern "C" void kernel_launch(void* const* d_in, const int* in_sizes, int n_in,
                              void* d_out, int out_size, void* d_ws, size_t ws_size,
                              hipStream_t stream) {
  const float* Q  = (const float*)d_in[0];
  const float* K  = (const float*)d_in[1];
  const float* V  = (const float*)d_in[2];
  const float* Wq = (const float*)d_in[3];
  const float* bq = (const float*)d_in[4];
  const float* Wk = (const float*)d_in[5];
  const float* bk = (const float*)d_in[6];
  const float* Wv = (const float*)d_in[7];
  const float* bv = (const float*)d_in[8];
  const float* Wo = (const float*)d_in[9];
  const float* bo = (const float*)d_in[10];
  float* out = (float*)d_out;

  u16* ws  = (u16*)d_ws;
  u16* Wt  = ws;                                   // 4 x 512*512 (q,k,v,o)
  u16* qws = Wt + 4 * 262144;                      // 8192*512 each (q,k,vT consecutive)
  u16* vTw = qws + (size_t)2 * 8192 * 512;
  u16* zws = qws + (size_t)3 * 8192 * 512;

  wtrans_k<<<dim3(1024, 4), 256, 0, stream>>>(Wq, Wk, Wv, Wo, Wt);
  qkv_k<<<dim3(256, 3), 256, 0, stream>>>(Q, K, V, Wt, bq, bk, bv, qws);
  attn_k<<<1024, 256, 0, stream>>>(qws, qws + (size_t)8192 * 512, vTw, zws);
  gemm_out_k<<<512, 256, 0, stream>>>(zws, Wt + 3 * 262144, bo, out);
}

// Round 10
// 146.837 us; speedup vs baseline: 1.0432x; 1.0432x over previous
//
#include <hip/hip_runtime.h>

// MHA: B=4, S=2048, D_MODEL=512, H=8, D_HEAD=64
// Wt transpose -> QKV proj GEMMs (one launch) -> flash attn -> out proj GEMM
// attn r10: K,V double-buffered via global_load_lds, one barrier per tile
// (r9 structure) BUT the P LDS round-trip is replaced by an in-register
// lane-bit-exchange (16 shfl_xor/tile) -> LDS 32KB (occupancy cliff at 40KB
// was r9's regression), no lgkmcnt fence, no sched_barrier, no race surface.

typedef unsigned short u16;
typedef __bf16 bf16x8 __attribute__((ext_vector_type(8)));
typedef float  f32x4  __attribute__((ext_vector_type(4)));

__device__ __forceinline__ u16 f2bf(float x) {
  unsigned u = __float_as_uint(x);
  u += 0x7fffu + ((u >> 16) & 1u);   // RNE
  return (u16)(u >> 16);
}

__device__ __forceinline__ unsigned cvtpk(float lo, float hi) {
  unsigned r;
  asm("v_cvt_pk_bf16_f32 %0, %1, %2" : "=v"(r) : "v"(lo), "v"(hi));
  return r;
}

__device__ __forceinline__ f32x4 mfma16(bf16x8 a, bf16x8 b, f32x4 c) {
  return __builtin_amdgcn_mfma_f32_16x16x32_bf16(a, b, c, 0, 0, 0);
}

__device__ __forceinline__ bf16x8 u4bf(uint4 v) {
  union { uint4 u; bf16x8 h; } c; c.u = v; return c.h;
}

// async 16B/lane global->LDS; lds dest is wave-uniform base (HW adds lane*16)
__device__ __forceinline__ void gl16(const u16* g, u16* l) {
  __builtin_amdgcn_global_load_lds(
      (const __attribute__((address_space(1))) void*)g,
      (__attribute__((address_space(3))) void*)l, 16, 0, 0);
}

#define MX3(a, b, c) fmaxf(fmaxf((a), (b)), (c))

// ---- W[k][n] fp32 -> Wt[n][k] bf16, all 4 weights in one launch ----
__global__ __launch_bounds__(256) void wtrans_k(const float* __restrict__ W0,
                                                const float* __restrict__ W1,
                                                const float* __restrict__ W2,
                                                const float* __restrict__ W3,
                                                u16* __restrict__ Wt) {
  int sel = blockIdx.y;
  const float* W = sel == 0 ? W0 : sel == 1 ? W1 : sel == 2 ? W2 : W3;
  int idx = blockIdx.x * 256 + threadIdx.x;
  int k = idx >> 9, n = idx & 511;
  Wt[sel * 262144 + n * 512 + k] = f2bf(W[idx]);
}

// ---- GEMM body: A[8192x512] @ Bt^T + bias (Bt is [n][k] bf16) ----
// OUT_MODE: 0 bf16 [m][n], 1 bf16 vT[(b*8+h)*64+d][s], 2 fp32 [m][n]
template <bool A_BF16, int OUT_MODE, int BN>
__device__ __forceinline__ void gemm_body(const void* __restrict__ Ap,
                                          const u16* __restrict__ Bt,
                                          const float* __restrict__ bias,
                                          void* __restrict__ outp, int bidx) {
  constexpr int NF = BN / 32;
  constexpr int NBN = 512 / BN;
  __shared__ __align__(16) u16 As[128][72];
  __shared__ __align__(16) u16 Bs[BN][72];
  int tid = threadIdx.x;
  int lane = tid & 63, wid = tid >> 6;
  int wm = wid >> 1, wn = wid & 1;
  int lr = lane & 15, lg = lane >> 4;
  int bm = bidx / NBN, bn = bidx % NBN;

  f32x4 acc[4][NF];
#pragma unroll
  for (int i = 0; i < 4; ++i)
#pragma unroll
    for (int j = 0; j < NF; ++j) {
      f32x4 z = {0.f, 0.f, 0.f, 0.f};
      acc[i][j] = z;
    }

  for (int kt = 0; kt < 8; ++kt) {
    int k0 = kt * 64;
    if (!A_BF16) {
      const float* A = (const float*)Ap;
#pragma unroll
      for (int i = 0; i < 8; ++i) {
        int idx = i * 256 + tid;
        int row = idx >> 4, c4 = idx & 15;
        float4 v = *(const float4*)(A + (size_t)(bm * 128 + row) * 512 + k0 + c4 * 4);
        ushort4 pk = make_ushort4(f2bf(v.x), f2bf(v.y), f2bf(v.z), f2bf(v.w));
        *(ushort4*)&As[row][c4 * 4] = pk;
      }
    } else {
      const u16* A = (const u16*)Ap;
#pragma unroll
      for (int i = 0; i < 4; ++i) {
        int idx = i * 256 + tid;
        int row = idx >> 3, c8 = idx & 7;
        uint4 v = *(const uint4*)(A + (size_t)(bm * 128 + row) * 512 + k0 + c8 * 8);
        *(uint4*)&As[row][c8 * 8] = v;
      }
    }
#pragma unroll
    for (int i = 0; i < BN / 32; ++i) {
      int idx = i * 256 + tid;
      int row = idx >> 3, c8 = idx & 7;
      uint4 v = *(const uint4*)(Bt + (size_t)(bn * BN + row) * 512 + k0 + c8 * 8);
      *(uint4*)&Bs[row][c8 * 8] = v;
    }
    __syncthreads();
#pragma unroll
    for (int kk = 0; kk < 2; ++kk) {
      bf16x8 af[4], bfr[NF];
#pragma unroll
      for (int mf = 0; mf < 4; ++mf)
        af[mf] = *(const bf16x8*)&As[wm * 64 + mf * 16 + lr][kk * 32 + lg * 8];
#pragma unroll
      for (int nf = 0; nf < NF; ++nf)
        bfr[nf] = *(const bf16x8*)&Bs[wn * (BN / 2) + nf * 16 + lr][kk * 32 + lg * 8];
#pragma unroll
      for (int mf = 0; mf < 4; ++mf)
#pragma unroll
        for (int nf = 0; nf < NF; ++nf)
          acc[mf][nf] = mfma16(af[mf], bfr[nf], acc[mf][nf]);
    }
    __syncthreads();
  }

#pragma unroll
  for (int mf = 0; mf < 4; ++mf) {
#pragma unroll
    for (int nf = 0; nf < NF; ++nf) {
      int m = bm * 128 + wm * 64 + mf * 16 + lg * 4;
      int n = bn * BN + wn * (BN / 2) + nf * 16 + lr;
      float bia = bias[n];
      if (OUT_MODE == 0) {
        u16* o = (u16*)outp;
#pragma unroll
        for (int r = 0; r < 4; ++r)
          o[(size_t)(m + r) * 512 + n] = f2bf(acc[mf][nf][r] + bia);
      } else if (OUT_MODE == 2) {
        float* o = (float*)outp;
#pragma unroll
        for (int r = 0; r < 4; ++r)
          o[(size_t)(m + r) * 512 + n] = acc[mf][nf][r] + bia;
      } else {
        u16* o = (u16*)outp;
        int b = m >> 11, s = m & 2047;
        int h = n >> 6, d = n & 63;
        ushort4 pk = make_ushort4(f2bf(acc[mf][nf][0] + bia), f2bf(acc[mf][nf][1] + bia),
                                  f2bf(acc[mf][nf][2] + bia), f2bf(acc[mf][nf][3] + bia));
        *(ushort4*)&o[(size_t)((b * 8 + h) * 64 + d) * 2048 + s] = pk;
      }
    }
  }
}

// QKV projections in one launch: blockIdx.y selects Q/K/V
__global__ __launch_bounds__(256) void qkv_k(const float* __restrict__ Q,
                                             const float* __restrict__ K,
                                             const float* __restrict__ V,
                                             const u16* __restrict__ Wt,
                                             const float* __restrict__ bq,
                                             const float* __restrict__ bk,
                                             const float* __restrict__ bv,
                                             u16* __restrict__ outbase) {
  int sel = blockIdx.y;
  const float* A = sel == 0 ? Q : sel == 1 ? K : V;
  const float* bia = sel == 0 ? bq : sel == 1 ? bk : bv;
  const u16* Bt = Wt + (size_t)sel * 262144;
  u16* out = outbase + (size_t)sel * 8192 * 512;
  if (sel == 2)
    gemm_body<false, 1, 128>(A, Bt, bia, out, blockIdx.x);
  else
    gemm_body<false, 0, 128>(A, Bt, bia, out, blockIdx.x);
}

__global__ __launch_bounds__(256) void gemm_out_k(const void* __restrict__ Ap,
                                                  const u16* __restrict__ Bt,
                                                  const float* __restrict__ bias,
                                                  void* __restrict__ outp) {
  gemm_body<true, 2, 64>(Ap, Bt, bias, outp, blockIdx.x);
}

// ---- flash attention ----
// S^T = mfma(K,Q): lane owns q = lane&15, keys nf*16+lg*4+r -> in-register softmax.
// O^T = mfma(V,P): oacc q-index = lane&15 -> per-lane m/l.
// P relayout (keys nf*16+lg*4+r -> ks*32+lg*8+j) done IN REGISTERS:
// key-bit4 <-> lane-bit5, key-bit2 <-> lane-bit4 exchange via shfl_xor(32),(16).
__global__ __launch_bounds__(256) void attn_k(const u16* __restrict__ q,
                                              const u16* __restrict__ kmat,
                                              const u16* __restrict__ vT,
                                              u16* __restrict__ z) {
  __shared__ __align__(16) u16 Ks[2][64][64];   // [buf][key][d], swizzled content
  __shared__ __align__(16) u16 Vs[2][64][64];   // [buf][d][key], swizzled content
  const float C = 0.125f * 1.44269504f;         // 1/sqrt(64) * log2(e)
  int tid = threadIdx.x;
  int lane = tid & 63, w = tid >> 6;
  int lr = lane & 15, lg = lane >> 4;
  bool lo4 = ((lane >> 4) & 1) == 0;            // lg bit0
  bool lo5 = (lane >> 5) == 0;                  // lg bit1
  int bh = blockIdx.x >> 5, qt = blockIdx.x & 31;
  int b = bh >> 3, h = bh & 7;
  size_t qrow0 = (size_t)(b * 2048 + qt * 64 + w * 16);

  // Q as B-fragment: lane holds Q[q=lr][d = kf*32 + lg*8 + j]
  bf16x8 qf[2];
#pragma unroll
  for (int kf = 0; kf < 2; ++kf)
    qf[kf] = *(const bf16x8*)&q[(qrow0 + lr) * 512 + h * 64 + kf * 32 + lg * 8];

  f32x4 oacc[4];
#pragma unroll
  for (int j = 0; j < 4; ++j) {
    f32x4 zf = {0.f, 0.f, 0.f, 0.f};
    oacc[j] = zf;
  }
  float m = -1e30f, l = 0.f, negmC = 0.f;

  const u16* kbase = kmat + (size_t)(b * 2048) * 512 + h * 64;
  const u16* vbase = vT + (size_t)(bh * 64) * 2048;

  // staging coords: LDS idx = i*256 + tid; row = idx>>3, c8dst = idx&7.
  // Pre-swizzled SOURCE column: c8src = c8dst ^ (row&7); row&7 == (tid>>3)&7.
  int r0 = tid >> 3;                         // 0..31
  int c8s = (tid & 7) ^ (r0 & 7);
  // prologue: K(0),V(0) -> buf0
  gl16(&kbase[(size_t)r0 * 512 + c8s * 8],        &Ks[0][0][0] + w * 512);
  gl16(&kbase[(size_t)(r0 + 32) * 512 + c8s * 8], &Ks[0][0][0] + 2048 + w * 512);
  gl16(&vbase[(size_t)r0 * 2048 + c8s * 8],        &Vs[0][0][0] + w * 512);
  gl16(&vbase[(size_t)(r0 + 32) * 2048 + c8s * 8], &Vs[0][0][0] + 2048 + w * 512);
  asm volatile("s_waitcnt vmcnt(0)" ::: "memory");
  __syncthreads();

  for (int kt = 0; kt < 32; ++kt) {
    int cur = kt & 1;
    // issue K(kt+1), V(kt+1) -> buf^1 (drained at end-of-tile barrier)
    if (kt < 31) {
      u16* KL = &Ks[cur ^ 1][0][0];
      u16* VL = &Vs[cur ^ 1][0][0];
      gl16(&kbase[(size_t)((kt + 1) * 64 + r0) * 512 + c8s * 8],       KL + w * 512);
      gl16(&kbase[(size_t)((kt + 1) * 64 + r0 + 32) * 512 + c8s * 8],  KL + 2048 + w * 512);
      gl16(&vbase[(size_t)r0 * 2048 + (kt + 1) * 64 + c8s * 8],        VL + w * 512);
      gl16(&vbase[(size_t)(r0 + 32) * 2048 + (kt + 1) * 64 + c8s * 8], VL + 2048 + w * 512);
    }

    // S^T = K @ Q^T : sacc[nf][r] = S[q=lr][key = nf*16 + lg*4 + r]
    f32x4 sacc[4];
#pragma unroll
    for (int j = 0; j < 4; ++j) {
      f32x4 zf = {0.f, 0.f, 0.f, 0.f};
      sacc[j] = zf;
    }
#pragma unroll
    for (int kf = 0; kf < 2; ++kf) {
#pragma unroll
      for (int nf = 0; nf < 4; ++nf) {
        int row = nf * 16 + lr;
        bf16x8 kb = *(const bf16x8*)&Ks[cur][row][(kf * 32 + lg * 8) ^ ((row & 7) << 3)];
        sacc[nf] = mfma16(kb, qf[kf], sacc[nf]);
      }
    }

    // V B-fragment prefetch (V(kt) resident since last barrier)
    bf16x8 vb[2][4];
#pragma unroll
    for (int ks = 0; ks < 2; ++ks)
#pragma unroll
      for (int nfo = 0; nfo < 4; ++nfo) {
        int row = nfo * 16 + lr;
        vb[ks][nfo] = *(const bf16x8*)&Vs[cur][row][(ks * 32 + lg * 8) ^ ((row & 7) << 3)];
      }

    // per-lane 16-value max via max3 triples
    float t0 = MX3(sacc[0][0], sacc[0][1], sacc[0][2]);
    float t1 = MX3(sacc[0][3], sacc[1][0], sacc[1][1]);
    float t2 = MX3(sacc[1][2], sacc[1][3], sacc[2][0]);
    float t3 = MX3(sacc[2][1], sacc[2][2], sacc[2][3]);
    float t4 = MX3(sacc[3][0], sacc[3][1], sacc[3][2]);
    float mxl = fmaxf(MX3(t0, t1, t2), MX3(t3, t4, sacc[3][3]));

    // defer-max (T13): cross-lane max + rescale only in the rare branch
    if (!__all(mxl - m <= 8.f)) {
      float mx = fmaxf(mxl, __shfl_xor(mxl, 16));
      mx = fmaxf(mx, __shfl_xor(mx, 32));
      float mnew = fmaxf(m, mx);
      float sc = __builtin_amdgcn_exp2f((m - mnew) * C);
      m = mnew;
      negmC = -m * C;
      l *= sc;
#pragma unroll
      for (int nfo = 0; nfo < 4; ++nfo)
#pragma unroll
        for (int r = 0; r < 4; ++r) oacc[nfo][r] *= sc;
    }

    // P = exp2(S*C - m*C); pack pairs: pw[nf][i] holds keys nf*16+lg*4+2i,+2i+1
    unsigned pw[4][2];
    float rsum = 0.f;
#pragma unroll
    for (int nf = 0; nf < 4; ++nf) {
      float p0 = __builtin_amdgcn_exp2f(fmaf(sacc[nf][0], C, negmC));
      float p1 = __builtin_amdgcn_exp2f(fmaf(sacc[nf][1], C, negmC));
      float p2 = __builtin_amdgcn_exp2f(fmaf(sacc[nf][2], C, negmC));
      float p3 = __builtin_amdgcn_exp2f(fmaf(sacc[nf][3], C, negmC));
      rsum += (p0 + p1) + (p2 + p3);
      pw[nf][0] = cvtpk(p0, p1);
      pw[nf][1] = cvtpk(p2, p3);
    }
    rsum += __shfl_xor(rsum, 16);
    rsum += __shfl_xor(rsum, 32);
    l += rsum;

    // O^T += V^T @ P^T with in-register P relayout per ks half:
    // needer (l4,l5) word t <- reg {u if l4==0 else u2}[t&1] of lane
    // (lane4 = t>>1, lane5 = own l5); u = family(l5) of holder(l4,0),
    // u2 = family(l5) of holder(l4,1). Verified routing on all 3 paths.
#pragma unroll
    for (int ks = 0; ks < 2; ++ks) {
      unsigned A0 = pw[2 * ks][0], A1 = pw[2 * ks][1];
      unsigned B0 = pw[2 * ks + 1][0], B1 = pw[2 * ks + 1][1];
      unsigned As0 = __shfl_xor(A0, 32), As1 = __shfl_xor(A1, 32);
      unsigned Bs0 = __shfl_xor(B0, 32), Bs1 = __shfl_xor(B1, 32);
      unsigned u0 = lo5 ? A0 : Bs0, u1 = lo5 ? A1 : Bs1;     // holder (l4,0)
      unsigned v0 = lo5 ? As0 : B0, v1 = lo5 ? As1 : B1;     // holder (l4,1)
      unsigned x0 = __shfl_xor(v0, 16), x1 = __shfl_xor(v1, 16);
      unsigned y0 = __shfl_xor(u0, 16), y1 = __shfl_xor(u1, 16);
      uint4 pv = make_uint4(lo4 ? u0 : x0, lo4 ? u1 : x1,
                            lo4 ? y0 : v0, lo4 ? y1 : v1);
      bf16x8 pa = u4bf(pv);
#pragma unroll
      for (int nfo = 0; nfo < 4; ++nfo)
        oacc[nfo] = mfma16(vb[ks][nfo], pa, oacc[nfo]);
    }

    // single end-of-tile barrier: K/V(kt+1) landed, all waves done with bufs
    asm volatile("s_waitcnt vmcnt(0)" ::: "memory");
    __syncthreads();
  }

  // normalize + vectorized store: lane owns q = lr, 4 consecutive d per nfo
  float rl = 1.f / l;
#pragma unroll
  for (int nfo = 0; nfo < 4; ++nfo) {
    uint2 ow = make_uint2(cvtpk(oacc[nfo][0] * rl, oacc[nfo][1] * rl),
                          cvtpk(oacc[nfo][2] * rl, oacc[nfo][3] * rl));
    *(uint2*)&z[(qrow0 + lr) * 512 + h * 64 + nfo * 16 + lg * 4] = ow;
  }
}

extern "C" void kernel_launch(void* const* d_in, const int* in_sizes, int n_in,
                              void* d_out, int out_size, void* d_ws, size_t ws_size,
                              hipStream_t stream) {
  const float* Q  = (const float*)d_in[0];
  const float* K  = (const float*)d_in[1];
  const float* V  = (const float*)d_in[2];
  const float* Wq = (const float*)d_in[3];
  const float* bq = (const float*)d_in[4];
  const float* Wk = (const float*)d_in[5];
  const float* bk = (const float*)d_in[6];
  const float* Wv = (const float*)d_in[7];
  const float* bv = (const float*)d_in[8];
  const float* Wo = (const float*)d_in[9];
  const float* bo = (const float*)d_in[10];
  float* out = (float*)d_out;

  u16* ws  = (u16*)d_ws;
  u16* Wt  = ws;                                   // 4 x 512*512 (q,k,v,o)
  u16* qws = Wt + 4 * 262144;                      // 8192*512 each (q,k,vT consecutive)
  u16* vTw = qws + (size_t)2 * 8192 * 512;
  u16* zws = qws + (size_t)3 * 8192 * 512;

  wtrans_k<<<dim3(1024, 4), 256, 0, stream>>>(Wq, Wk, Wv, Wo, Wt);
  qkv_k<<<dim3(256, 3), 256, 0, stream>>>(Q, K, V, Wt, bq, bk, bv, qws);
  attn_k<<<1024, 256, 0, stream>>>(qws, qws + (size_t)8192 * 512, vTw, zws);
  gemm_out_k<<<512, 256, 0, stream>>>(zws, Wt + 3 * 262144, bo, out);
}